// Round 1
// baseline (225.743 us; speedup 1.0000x reference)
//
#include <hip/hip_runtime.h>
#include <hip/hip_bf16.h>
#include <cstdint>

#define TOKENS 8192
#define DIN    2048
#define UNITS  2048

#define BM 128
#define BN 128
#define BK 32

typedef float  f32x4  __attribute__((ext_vector_type(4)));
typedef __bf16 bf16x8 __attribute__((ext_vector_type(8)));

__device__ __forceinline__ unsigned short f32_to_bf16_rne(float f) {
  unsigned int u = __float_as_uint(f);
  u += 0x7FFFu + ((u >> 16) & 1u);
  return (unsigned short)(u >> 16);
}

__device__ __forceinline__ void global_load_lds16(const void* g, void* l) {
  __builtin_amdgcn_global_load_lds(
      (const __attribute__((address_space(1))) unsigned int*)g,
      (__attribute__((address_space(3))) unsigned int*)l,
      16, 0, 0);
}

// ---- kernel 1: x fp32 -> bf16 (RNE), float4 vectorized ----
__global__ void cvt_x_kernel(const float* __restrict__ x,
                             unsigned short* __restrict__ xb, int n4) {
  int i = blockIdx.x * blockDim.x + threadIdx.x;
  const int stride = gridDim.x * blockDim.x;
  for (; i < n4; i += stride) {
    const float4 v = reinterpret_cast<const float4*>(x)[i];
    ushort4 o;
    o.x = f32_to_bf16_rne(v.x);
    o.y = f32_to_bf16_rne(v.y);
    o.z = f32_to_bf16_rne(v.z);
    o.w = f32_to_bf16_rne(v.w);
    reinterpret_cast<ushort4*>(xb)[i] = o;
  }
}

// ---- kernel 2: Wt[u][k] = sign(W[k][u]) as bf16 +/-1, LDS transpose ----
__global__ void sign_transpose_kernel(const float* __restrict__ W,
                                      unsigned short* __restrict__ Wt) {
  __shared__ unsigned short tile[32][33];
  const int u0 = blockIdx.x * 32;
  const int k0 = blockIdx.y * 32;
  const int tx = threadIdx.x;  // 0..31
  const int ty = threadIdx.y;  // 0..7
#pragma unroll
  for (int j = 0; j < 32; j += 8) {
    const int k = k0 + ty + j;
    const int u = u0 + tx;
    const float w = W[(size_t)k * UNITS + u];
    tile[tx][ty + j] = (w >= 0.0f) ? (unsigned short)0x3F80u
                                   : (unsigned short)0xBF80u;
  }
  __syncthreads();
#pragma unroll
  for (int j = 0; j < 32; j += 8) {
    const int u = u0 + ty + j;
    const int k = k0 + tx;
    Wt[(size_t)u * DIN + k] = tile[ty + j][tx];
  }
}

// ---- kernel 3: bf16 MFMA GEMM, m97 structure ----
// A: [TOKENS][DIN] bf16 row-major; Bt: [UNITS][DIN] bf16 row-major (B^T).
// C: [TOKENS][UNITS] fp32.
__global__ __launch_bounds__(256) void gemm_bin_kernel(
    const unsigned short* __restrict__ A,
    const unsigned short* __restrict__ Bt,
    float* __restrict__ C) {
  __shared__ unsigned short As[BM * BK];  // 8 KB
  __shared__ unsigned short Bs[BN * BK];  // 8 KB

  // XCD-aware bijective swizzle (nwg = 1024, divisible by 8)
  const int nwg = gridDim.x;
  const int bid = blockIdx.x;
  const int q = nwg >> 3;
  const int swz = (bid & 7) * q + (bid >> 3);
  const int tiles_n = UNITS / BN;  // 16
  const int tm = swz / tiles_n;
  const int tn = swz % tiles_n;
  const int brow = tm * BM;
  const int bcol = tn * BN;

  const int tid  = threadIdx.x;
  const int lane = tid & 63;
  const int w    = tid >> 6;  // wave 0..3
  const int wr   = w >> 1;    // 0..1 (M)
  const int wc   = w & 1;     // 0..1 (N)
  const int l15  = lane & 15;
  const int l4   = lane >> 4;

  // staging: 16B per thread per call; 2 calls cover a 128x32 bf16 tile
  const int srow  = tid >> 2;        // 0..63
  const int scol8 = (tid & 3) * 8;   // bf16-element offset in row

  f32x4 acc[4][4];
#pragma unroll
  for (int i = 0; i < 4; ++i)
#pragma unroll
    for (int j = 0; j < 4; ++j)
#pragma unroll
      for (int r = 0; r < 4; ++r) acc[i][j][r] = 0.0f;

  for (int kt = 0; kt < DIN; kt += BK) {
#pragma unroll
    for (int h = 0; h < 2; ++h) {
      const int r = h * 64 + srow;
      global_load_lds16(&A[(size_t)(brow + r) * DIN + kt + scol8],
                        &As[r * BK + scol8]);
      global_load_lds16(&Bt[(size_t)(bcol + r) * DIN + kt + scol8],
                        &Bs[r * BK + scol8]);
    }
    __syncthreads();  // drains vmcnt before barrier

    bf16x8 af[4], bfv[4];
#pragma unroll
    for (int f = 0; f < 4; ++f) {
      af[f]  = *reinterpret_cast<const bf16x8*>(
          &As[(wr * 64 + f * 16 + l15) * BK + l4 * 8]);
      bfv[f] = *reinterpret_cast<const bf16x8*>(
          &Bs[(wc * 64 + f * 16 + l15) * BK + l4 * 8]);
    }
#pragma unroll
    for (int i = 0; i < 4; ++i)
#pragma unroll
      for (int j = 0; j < 4; ++j)
        acc[i][j] = __builtin_amdgcn_mfma_f32_16x16x32_bf16(
            af[i], bfv[j], acc[i][j], 0, 0, 0);
    __syncthreads();
  }

  // epilogue: C/D layout col=lane&15, row=(lane>>4)*4+r  [m89/m91-verified]
  float* Cp = C + (size_t)(brow + wr * 64) * UNITS + (bcol + wc * 64);
#pragma unroll
  for (int i = 0; i < 4; ++i)
#pragma unroll
    for (int j = 0; j < 4; ++j)
#pragma unroll
      for (int r = 0; r < 4; ++r) {
        const int row = i * 16 + l4 * 4 + r;
        const int col = j * 16 + l15;
        Cp[(size_t)row * UNITS + col] = acc[i][j][r];
      }
}

extern "C" void kernel_launch(void* const* d_in, const int* in_sizes, int n_in,
                              void* d_out, int out_size, void* d_ws, size_t ws_size,
                              hipStream_t stream) {
  const float* x = (const float*)d_in[0];
  const float* W = (const float*)d_in[1];
  float* out = (float*)d_out;

  unsigned short* xb = (unsigned short*)d_ws;                 // 32 MB
  unsigned short* Wt = xb + (size_t)TOKENS * DIN;             // 8 MB

  cvt_x_kernel<<<2048, 256, 0, stream>>>(x, xb, TOKENS * DIN / 4);

  dim3 gT(UNITS / 32, DIN / 32), bT(32, 8);
  sign_transpose_kernel<<<gT, bT, 0, stream>>>(W, Wt);

  const int grid = (TOKENS / BM) * (UNITS / BN);  // 1024
  gemm_bin_kernel<<<grid, 256, 0, stream>>>(xb, Wt, out);
}

// Round 3
// 207.899 us; speedup vs baseline: 1.0858x; 1.0858x over previous
//
#include <hip/hip_runtime.h>
#include <hip/hip_bf16.h>
#include <cstdint>

#define TOKENS 8192
#define DIN    2048
#define UNITS  2048

#define BMT 256
#define BNT 256
#define BKS 64
#define NKSTEP (DIN / BKS)   // 32
#define NITER  (NKSTEP / 2)  // 16

typedef float  f32x4  __attribute__((ext_vector_type(4)));
typedef __bf16 bf16x8 __attribute__((ext_vector_type(8)));
typedef __attribute__((address_space(3))) unsigned char lds_byte_t;
typedef __attribute__((address_space(3))) unsigned int  lds_uint_t;
typedef const __attribute__((address_space(1))) unsigned int g_uint_t;

// LDS map: A: [buf][half] 16KB each at 0..64K; B: same at 64K..128K
#define A_OFF(buf, h) ((buf) * 32768 + (h) * 16384)
#define B_OFF(buf, c) (65536 + (buf) * 32768 + (c) * 16384)

__device__ __forceinline__ unsigned short f32_to_bf16_rne(float f) {
  unsigned int u = __float_as_uint(f);
  u += 0x7FFFu + ((u >> 16) & 1u);
  return (unsigned short)(u >> 16);
}

__device__ __forceinline__ bf16x8 ds_read_b128f(uint32_t addr) {
  bf16x8 r;
  asm volatile("ds_read_b128 %0, %1" : "=v"(r) : "v"(addr));
  return r;
}

// ---- kernel 1: x fp32 -> bf16 (RNE) ----
__global__ void cvt_x_kernel(const float* __restrict__ x,
                             unsigned short* __restrict__ xb, int n4) {
  int i = blockIdx.x * blockDim.x + threadIdx.x;
  const int stride = gridDim.x * blockDim.x;
  for (; i < n4; i += stride) {
    const float4 v = reinterpret_cast<const float4*>(x)[i];
    ushort4 o;
    o.x = f32_to_bf16_rne(v.x);
    o.y = f32_to_bf16_rne(v.y);
    o.z = f32_to_bf16_rne(v.z);
    o.w = f32_to_bf16_rne(v.w);
    reinterpret_cast<ushort4*>(xb)[i] = o;
  }
}

// ---- kernel 2: Wt[u][k] = sign(W[k][u]) bf16 +/-1 ----
__global__ void sign_transpose_kernel(const float* __restrict__ W,
                                      unsigned short* __restrict__ Wt) {
  __shared__ unsigned short tile[32][33];
  const int u0 = blockIdx.x * 32;
  const int k0 = blockIdx.y * 32;
  const int tx = threadIdx.x;
  const int ty = threadIdx.y;
#pragma unroll
  for (int j = 0; j < 32; j += 8) {
    const float w = W[(size_t)(k0 + ty + j) * UNITS + u0 + tx];
    tile[tx][ty + j] = (w >= 0.0f) ? (unsigned short)0x3F80u
                                   : (unsigned short)0xBF80u;
  }
  __syncthreads();
#pragma unroll
  for (int j = 0; j < 32; j += 8)
    Wt[(size_t)(u0 + ty + j) * DIN + k0 + tx] = tile[ty + j][tx];
}

// ---- kernel 3: 256x256 8-phase bf16 MFMA GEMM ----
__global__ __launch_bounds__(512, 2) void gemm8_kernel(
    const unsigned short* __restrict__ A,
    const unsigned short* __restrict__ Bt,
    float* __restrict__ C) {
  extern __shared__ char smem_raw[];
  lds_byte_t* sm = (lds_byte_t*)smem_raw;
  const uint32_t smbase = (uint32_t)(uintptr_t)sm;

  const int tid  = threadIdx.x;
  const int lane = tid & 63;
  const int w    = tid >> 6;   // 0..7
  const int wr   = w >> 2;     // 0..1 (M half of wave grid)
  const int wc   = w & 3;      // 0..3 (N quarter)
  const int l15  = lane & 15;
  const int l4   = lane >> 4;  // 0..3
  const int ln8  = lane >> 3;  // 0..7
  const int la7  = lane & 7;

  // bijective XCD swizzle: nwg=256, q=32
  const int bid  = blockIdx.x;
  const int swzb = (bid & 7) * 32 + (bid >> 3);
  const int tm = swzb >> 3, tn = swzb & 7;   // 32 x 8 tiles
  const int m0 = tm * BMT, n0 = tn * BNT;

  // staging constants: per call, wave w covers 8 rows; lane -> row w*8+ln8,
  // 16B phys slot la7; source column pre-swizzled (inverse of read XOR).
  const int stg_colel = ((la7 ^ ln8) << 3);            // element offset in K-step
  const int stg_lds   = w * 1024 + lane * 16;          // + n*8192 per call

  // read constants: phys in-row byte = (s*64 + l4*16) ^ ((row&7)<<4), row&7==la7
  const int xsw   = la7 << 4;
  const int koff0 = (0 * 64 + l4 * 16) ^ xsw;
  const int koff1 = (1 * 64 + l4 * 16) ^ xsw;
  const uint32_t a_rb = (uint32_t)(wr * 64 + l15) * 128;  // + i*2048 + koff
  const uint32_t b_rb = (uint32_t)(wc * 32 + l15) * 128;  // + jj*2048 + koff

  bf16x8 Af[4][2], Bf[2][2];
  f32x4 acc[2][4][2][2];
#pragma unroll
  for (int h = 0; h < 2; ++h)
#pragma unroll
    for (int i = 0; i < 4; ++i)
#pragma unroll
      for (int c = 0; c < 2; ++c)
#pragma unroll
        for (int j = 0; j < 2; ++j)
#pragma unroll
          for (int r = 0; r < 4; ++r) acc[h][i][c][j][r] = 0.0f;

#define STAGE_A(buf, h, ks) do { if ((ks) < NKSTEP) { \
    _Pragma("unroll") for (int n_ = 0; n_ < 2; ++n_) { \
      const size_t gr_ = (size_t)(m0 + (h) * 128 + n_ * 64 + w * 8 + ln8) * DIN \
                         + (size_t)(ks) * 64 + stg_colel; \
      __builtin_amdgcn_global_load_lds((g_uint_t*)(const void*)(A + gr_), \
          (lds_uint_t*)(sm + A_OFF(buf, (h)) + n_ * 8192 + stg_lds), 16, 0, 0); \
    } } } while (0)

#define STAGE_B(buf, c, ks) do { if ((ks) < NKSTEP) { \
    _Pragma("unroll") for (int n_ = 0; n_ < 2; ++n_) { \
      const size_t gr_ = (size_t)(n0 + (c) * 128 + n_ * 64 + w * 8 + ln8) * DIN \
                         + (size_t)(ks) * 64 + stg_colel; \
      __builtin_amdgcn_global_load_lds((g_uint_t*)(const void*)(Bt + gr_), \
          (lds_uint_t*)(sm + B_OFF(buf, (c)) + n_ * 8192 + stg_lds), 16, 0, 0); \
    } } } while (0)

#define PHASE(buf, h, c, LOADA, LOADB, STAGECALL, VM) do { \
  if (LOADA) { _Pragma("unroll") for (int i_ = 0; i_ < 4; ++i_) { \
      Af[i_][0] = ds_read_b128f(smbase + A_OFF(buf, (h)) + a_rb + i_ * 2048 + koff0); \
      Af[i_][1] = ds_read_b128f(smbase + A_OFF(buf, (h)) + a_rb + i_ * 2048 + koff1); } } \
  if (LOADB) { _Pragma("unroll") for (int j_ = 0; j_ < 2; ++j_) { \
      Bf[j_][0] = ds_read_b128f(smbase + B_OFF(buf, (c)) + b_rb + j_ * 2048 + koff0); \
      Bf[j_][1] = ds_read_b128f(smbase + B_OFF(buf, (c)) + b_rb + j_ * 2048 + koff1); } } \
  STAGECALL; \
  __builtin_amdgcn_s_barrier(); \
  asm volatile("s_waitcnt lgkmcnt(0)" ::: "memory"); \
  __builtin_amdgcn_sched_barrier(0); \
  __builtin_amdgcn_s_setprio(1); \
  _Pragma("unroll") for (int i_ = 0; i_ < 4; ++i_) \
  _Pragma("unroll") for (int j_ = 0; j_ < 2; ++j_) { \
    acc[h][i_][c][j_] = __builtin_amdgcn_mfma_f32_16x16x32_bf16( \
        Af[i_][0], Bf[j_][0], acc[h][i_][c][j_], 0, 0, 0); \
    acc[h][i_][c][j_] = __builtin_amdgcn_mfma_f32_16x16x32_bf16( \
        Af[i_][1], Bf[j_][1], acc[h][i_][c][j_], 0, 0, 0); } \
  __builtin_amdgcn_s_setprio(0); \
  if ((VM) >= 0) { \
    if ((VM) == 0) asm volatile("s_waitcnt vmcnt(0)" ::: "memory"); \
    else           asm volatile("s_waitcnt vmcnt(4)" ::: "memory"); } \
  __builtin_amdgcn_s_barrier(); \
} while (0)

  // prologue: buf0 <- K0 (all 4 half-tiles), buf1 <- K1 {Bh0, Ah1}
  STAGE_A(0, 0, 0); STAGE_A(0, 1, 0); STAGE_B(0, 0, 0); STAGE_B(0, 1, 0);
  STAGE_B(1, 0, 1); STAGE_A(1, 1, 1);
  asm volatile("s_waitcnt vmcnt(4)" ::: "memory");
  __builtin_amdgcn_s_barrier();

  for (int j = 0; j < NITER; ++j) {
    const int k1 = 2 * j + 1, k2 = 2 * j + 2, k3 = 2 * j + 3;
    const int vm4 = (j == NITER - 1) ? 0 : 4;
    // buf0 quadrants (Gray): Q00, Q10, Q11, Q01
    PHASE(0, 0, 0, 1, 1, STAGE_A(1, 0, k1), -1);  // P1: stage Ah0->buf1
    PHASE(0, 1, 0, 1, 0, STAGE_B(1, 1, k1), -1);  // P2: stage Bh1->buf1
    PHASE(0, 1, 1, 0, 1, STAGE_B(0, 0, k2), -1);  // P3: stage Bh0->buf0
    PHASE(0, 0, 1, 1, 0, STAGE_A(0, 1, k2), vm4); // P4: stage Ah1->buf0, vmcnt
    // buf1 quadrants
    PHASE(1, 0, 0, 1, 1, STAGE_A(0, 0, k2), -1);  // P5: stage Ah0->buf0
    PHASE(1, 1, 0, 1, 0, STAGE_B(0, 1, k2), -1);  // P6: stage Bh1->buf0
    PHASE(1, 1, 1, 0, 1, STAGE_B(1, 0, k3), -1);  // P7: stage Bh0->buf1
    PHASE(1, 0, 1, 1, 0, STAGE_A(1, 1, k3), 4);   // P8: stage Ah1->buf1, vmcnt
  }

  // epilogue: C/D layout col=lane&15, row=(lane>>4)*4+r
#pragma unroll
  for (int h = 0; h < 2; ++h)
#pragma unroll
    for (int cc = 0; cc < 2; ++cc)
#pragma unroll
      for (int i = 0; i < 4; ++i)
#pragma unroll
        for (int jj = 0; jj < 2; ++jj)
#pragma unroll
          for (int r = 0; r < 4; ++r) {
            const int row = m0 + h * 128 + wr * 64 + i * 16 + l4 * 4 + r;
            const int col = n0 + cc * 128 + wc * 32 + jj * 16 + l15;
            C[(size_t)row * UNITS + col] = acc[h][i][cc][jj][r];
          }
#undef STAGE_A
#undef STAGE_B
#undef PHASE
}

extern "C" void kernel_launch(void* const* d_in, const int* in_sizes, int n_in,
                              void* d_out, int out_size, void* d_ws, size_t ws_size,
                              hipStream_t stream) {
  const float* x = (const float*)d_in[0];
  const float* W = (const float*)d_in[1];
  float* out = (float*)d_out;

  unsigned short* xb = (unsigned short*)d_ws;       // 32 MB
  unsigned short* Wt = xb + (size_t)TOKENS * DIN;   // 8 MB

  cvt_x_kernel<<<2048, 256, 0, stream>>>(x, xb, TOKENS * DIN / 4);

  dim3 gT(UNITS / 32, DIN / 32), bT(32, 8);
  sign_transpose_kernel<<<gT, bT, 0, stream>>>(W, Wt);

  (void)hipFuncSetAttribute((const void*)gemm8_kernel,
                            hipFuncAttributeMaxDynamicSharedMemorySize, 131072);
  const int grid = (TOKENS / BMT) * (UNITS / BNT);  // 256
  gemm8_kernel<<<grid, 512, 131072, stream>>>(xb, Wt, out);
}

// Round 6
// 203.800 us; speedup vs baseline: 1.1077x; 1.0201x over previous
//
#include <hip/hip_runtime.h>
#include <hip/hip_bf16.h>
#include <cstdint>

#define TOKENS 8192
#define DIN    2048
#define UNITS  2048

#define BMT 256
#define BNT 256
#define BKS 64
#define NKSTEP (DIN / BKS)   // 32
#define NITER  (NKSTEP / 2)  // 16

typedef float  f32x4  __attribute__((ext_vector_type(4)));
typedef __bf16 bf16x8 __attribute__((ext_vector_type(8)));
typedef __attribute__((address_space(3))) unsigned char lds_byte_t;
typedef __attribute__((address_space(3))) unsigned int  lds_uint_t;
typedef const __attribute__((address_space(1))) unsigned int g_uint_t;

// LDS map: A: [buf][half] 16KB each at 0..64K; B: same at 64K..128K
#define A_OFF(buf, h) ((buf) * 32768 + (h) * 16384)
#define B_OFF(buf, c) (65536 + (buf) * 32768 + (c) * 16384)

__device__ __forceinline__ unsigned short f32_to_bf16_rne(float f) {
  unsigned int u = __float_as_uint(f);
  u += 0x7FFFu + ((u >> 16) & 1u);
  return (unsigned short)(u >> 16);
}

__device__ __forceinline__ bf16x8 ds_read_b128f(uint32_t addr) {
  bf16x8 r;
  asm volatile("ds_read_b128 %0, %1" : "=v"(r) : "v"(addr));
  return r;
}

// ---- kernel 1: x fp32 -> bf16 (RNE) ----
__global__ void cvt_x_kernel(const float* __restrict__ x,
                             unsigned short* __restrict__ xb, int n4) {
  int i = blockIdx.x * blockDim.x + threadIdx.x;
  const int stride = gridDim.x * blockDim.x;
  for (; i < n4; i += stride) {
    const float4 v = reinterpret_cast<const float4*>(x)[i];
    ushort4 o;
    o.x = f32_to_bf16_rne(v.x);
    o.y = f32_to_bf16_rne(v.y);
    o.z = f32_to_bf16_rne(v.z);
    o.w = f32_to_bf16_rne(v.w);
    reinterpret_cast<ushort4*>(xb)[i] = o;
  }
}

// ---- kernel 2: Wt[u][k] = sign(W[k][u]) bf16 +/-1 ----
__global__ void sign_transpose_kernel(const float* __restrict__ W,
                                      unsigned short* __restrict__ Wt) {
  __shared__ unsigned short tile[32][33];
  const int u0 = blockIdx.x * 32;
  const int k0 = blockIdx.y * 32;
  const int tx = threadIdx.x;
  const int ty = threadIdx.y;
#pragma unroll
  for (int j = 0; j < 32; j += 8) {
    const float w = W[(size_t)(k0 + ty + j) * UNITS + u0 + tx];
    tile[tx][ty + j] = (w >= 0.0f) ? (unsigned short)0x3F80u
                                   : (unsigned short)0xBF80u;
  }
  __syncthreads();
#pragma unroll
  for (int j = 0; j < 32; j += 8)
    Wt[(size_t)(u0 + ty + j) * DIN + k0 + tx] = tile[ty + j][tx];
}

// ---- kernel 3: 256x256 8-phase bf16 MFMA GEMM ----
// Single barrier per phase; stage slot = region's last-read phase + 1;
// vmcnt(6) at P4/P8 (vmcnt(0) at last iteration's P4); c-first quadrant walk.
__global__ __launch_bounds__(512, 2) void gemm8_kernel(
    const unsigned short* __restrict__ A,
    const unsigned short* __restrict__ Bt,
    float* __restrict__ C) {
  extern __shared__ char smem_raw[];
  lds_byte_t* sm = (lds_byte_t*)smem_raw;
  const uint32_t smbase = (uint32_t)(uintptr_t)sm;

  const int tid  = threadIdx.x;
  const int lane = tid & 63;
  const int w    = tid >> 6;   // 0..7
  const int wr   = w >> 2;     // 0..1 (M half of wave grid)
  const int wc   = w & 3;      // 0..3 (N quarter)
  const int l15  = lane & 15;
  const int l4   = lane >> 4;  // 0..3
  const int ln8  = lane >> 3;  // 0..7
  const int la7  = lane & 7;

  // bijective XCD swizzle: nwg=256, q=32
  const int bid  = blockIdx.x;
  const int swzb = (bid & 7) * 32 + (bid >> 3);
  const int tm = swzb >> 3, tn = swzb & 7;   // 32 x 8 tiles
  const int m0 = tm * BMT, n0 = tn * BNT;

  // staging: lane -> row w*8+ln8, 16B phys slot la7; source col pre-swizzled
  const int stg_colel = ((la7 ^ ln8) << 3);   // element offset in K-step
  const int stg_lds   = w * 1024 + lane * 16; // + n*8192 per call

  // reads: phys in-row byte = (s*64 + l4*16) ^ ((row&7)<<4), row&7 == la7
  const int xsw   = la7 << 4;
  const int koff0 = (0 * 64 + l4 * 16) ^ xsw;
  const int koff1 = (1 * 64 + l4 * 16) ^ xsw;
  const uint32_t a_rb = (uint32_t)(wr * 64 + l15) * 128;  // + i*2048 + koff
  const uint32_t b_rb = (uint32_t)(wc * 32 + l15) * 128;  // + jj*2048 + koff

  bf16x8 Af[4][2], Bf[2][2];
  f32x4 acc[2][4][2][2];
#pragma unroll
  for (int h = 0; h < 2; ++h)
#pragma unroll
    for (int i = 0; i < 4; ++i)
#pragma unroll
      for (int c = 0; c < 2; ++c)
#pragma unroll
        for (int j = 0; j < 2; ++j)
#pragma unroll
          for (int r = 0; r < 4; ++r) acc[h][i][c][j][r] = 0.0f;

#define STAGE_A(buf, h, ks) do { if ((ks) < NKSTEP) { \
    _Pragma("unroll") for (int n_ = 0; n_ < 2; ++n_) { \
      const size_t gr_ = (size_t)(m0 + (h) * 128 + n_ * 64 + w * 8 + ln8) * DIN \
                         + (size_t)(ks) * 64 + stg_colel; \
      __builtin_amdgcn_global_load_lds((g_uint_t*)(const void*)(A + gr_), \
          (lds_uint_t*)(sm + A_OFF(buf, (h)) + n_ * 8192 + stg_lds), 16, 0, 0); \
    } } } while (0)

#define STAGE_B(buf, c, ks) do { if ((ks) < NKSTEP) { \
    _Pragma("unroll") for (int n_ = 0; n_ < 2; ++n_) { \
      const size_t gr_ = (size_t)(n0 + (c) * 128 + n_ * 64 + w * 8 + ln8) * DIN \
                         + (size_t)(ks) * 64 + stg_colel; \
      __builtin_amdgcn_global_load_lds((g_uint_t*)(const void*)(Bt + gr_), \
          (lds_uint_t*)(sm + B_OFF(buf, (c)) + n_ * 8192 + stg_lds), 16, 0, 0); \
    } } } while (0)

// Phase: [reads | stage | lgkm0 | MFMA | (vmcnt) | barrier]
// VM: -1 none, 0 -> vmcnt(0), 6 -> vmcnt(6)
#define PHASE(buf, h, c, LOADA, LOADB, STAGECALL, VM) do { \
  if (LOADA) { _Pragma("unroll") for (int i_ = 0; i_ < 4; ++i_) { \
      Af[i_][0] = ds_read_b128f(smbase + A_OFF(buf, (h)) + a_rb + i_ * 2048 + koff0); \
      Af[i_][1] = ds_read_b128f(smbase + A_OFF(buf, (h)) + a_rb + i_ * 2048 + koff1); } } \
  if (LOADB) { _Pragma("unroll") for (int j_ = 0; j_ < 2; ++j_) { \
      Bf[j_][0] = ds_read_b128f(smbase + B_OFF(buf, (c)) + b_rb + j_ * 2048 + koff0); \
      Bf[j_][1] = ds_read_b128f(smbase + B_OFF(buf, (c)) + b_rb + j_ * 2048 + koff1); } } \
  STAGECALL; \
  asm volatile("s_waitcnt lgkmcnt(0)" ::: "memory"); \
  __builtin_amdgcn_sched_barrier(0); \
  __builtin_amdgcn_s_setprio(1); \
  _Pragma("unroll") for (int i_ = 0; i_ < 4; ++i_) \
  _Pragma("unroll") for (int j_ = 0; j_ < 2; ++j_) { \
    acc[h][i_][c][j_] = __builtin_amdgcn_mfma_f32_16x16x32_bf16( \
        Af[i_][0], Bf[j_][0], acc[h][i_][c][j_], 0, 0, 0); \
    acc[h][i_][c][j_] = __builtin_amdgcn_mfma_f32_16x16x32_bf16( \
        Af[i_][1], Bf[j_][1], acc[h][i_][c][j_], 0, 0, 0); } \
  __builtin_amdgcn_s_setprio(0); \
  if ((VM) == 0)      { asm volatile("s_waitcnt vmcnt(0)" ::: "memory"); } \
  else if ((VM) > 0)  { asm volatile("s_waitcnt vmcnt(6)" ::: "memory"); } \
  __builtin_amdgcn_s_barrier(); \
} while (0)

  // prologue: buf0 <- k0 (8 loads, oldest), buf1 <- k1 {A(1,0), B(1,1), A(1,1)}
  STAGE_A(0, 0, 0); STAGE_B(0, 1, 0); STAGE_A(0, 1, 0); STAGE_B(0, 0, 0);
  STAGE_A(1, 0, 1); STAGE_B(1, 1, 1); STAGE_A(1, 1, 1);
  asm volatile("s_waitcnt vmcnt(6)" ::: "memory");  // drains buf0's 8
  __builtin_amdgcn_s_barrier();

  for (int j = 0; j < NITER; ++j) {
    const int k1 = 2 * j + 1, k2 = 2 * j + 2, k3 = 2 * j + 3;
    const int vmA = (j == NITER - 1) ? 0 : 6;
    // buf0, c-first walk: (h0,c0) (h0,c1) (h1,c1) (h1,c0)
    PHASE(0, 0, 0, 1, 1, STAGE_B(1, 0, k1), -1);   // P1
    PHASE(0, 0, 1, 0, 1, STAGE_A(0, 0, k2), -1);   // P2
    PHASE(0, 1, 1, 1, 0, STAGE_B(0, 1, k2), -1);   // P3
    PHASE(0, 1, 0, 0, 1, STAGE_A(0, 1, k2), vmA);  // P4 (re-read B(0,0))
    // buf1
    PHASE(1, 0, 0, 1, 1, STAGE_B(0, 0, k2), -1);   // P5
    PHASE(1, 0, 1, 0, 1, STAGE_A(1, 0, k3), -1);   // P6
    PHASE(1, 1, 1, 1, 0, STAGE_B(1, 1, k3), -1);   // P7
    PHASE(1, 1, 0, 0, 1, STAGE_A(1, 1, k3), 6);    // P8 (re-read B(1,0))
  }

  // epilogue: C/D layout col=lane&15, row=(lane>>4)*4+r
#pragma unroll
  for (int h = 0; h < 2; ++h)
#pragma unroll
    for (int cc = 0; cc < 2; ++cc)
#pragma unroll
      for (int i = 0; i < 4; ++i)
#pragma unroll
        for (int jj = 0; jj < 2; ++jj)
#pragma unroll
          for (int r = 0; r < 4; ++r) {
            const int row = m0 + h * 128 + wr * 64 + i * 16 + l4 * 4 + r;
            const int col = n0 + cc * 128 + wc * 32 + jj * 16 + l15;
            C[(size_t)row * UNITS + col] = acc[h][i][cc][jj][r];
          }
#undef STAGE_A
#undef STAGE_B
#undef PHASE
}

extern "C" void kernel_launch(void* const* d_in, const int* in_sizes, int n_in,
                              void* d_out, int out_size, void* d_ws, size_t ws_size,
                              hipStream_t stream) {
  const float* x = (const float*)d_in[0];
  const float* W = (const float*)d_in[1];
  float* out = (float*)d_out;

  unsigned short* xb = (unsigned short*)d_ws;       // 32 MB
  unsigned short* Wt = xb + (size_t)TOKENS * DIN;   // 8 MB

  cvt_x_kernel<<<2048, 256, 0, stream>>>(x, xb, TOKENS * DIN / 4);

  dim3 gT(UNITS / 32, DIN / 32), bT(32, 8);
  sign_transpose_kernel<<<gT, bT, 0, stream>>>(W, Wt);

  (void)hipFuncSetAttribute((const void*)gemm8_kernel,
                            hipFuncAttributeMaxDynamicSharedMemorySize, 131072);
  const int grid = (TOKENS / BMT) * (UNITS / BNT);  // 256
  gemm8_kernel<<<grid, 512, 131072, stream>>>(xb, Wt, out);
}